// Round 1
// baseline (1317.182 us; speedup 1.0000x reference)
//
#include <hip/hip_runtime.h>
#include <hip/hip_bf16.h>

#define T_TOK 8192
#define DD 1024
#define EE 8
#define HH 4096

typedef __bf16 bf16_t;
typedef __bf16 bf16x8 __attribute__((ext_vector_type(8)));
typedef __bf16 bf16x4 __attribute__((ext_vector_type(4)));
typedef float f32x4 __attribute__((ext_vector_type(4)));

#define GLDS(g, l) __builtin_amdgcn_global_load_lds( \
    (const __attribute__((address_space(1))) void*)(g), \
    (__attribute__((address_space(3))) void*)(l), 16, 0, 0)

// ---------------- LayerNorm + gating ----------------
__global__ __launch_bounds__(256) void ln_gate_kernel(
    const float* __restrict__ x, const float* __restrict__ gamma,
    const float* __restrict__ beta, const float* __restrict__ gate_w,
    bf16_t* __restrict__ xn, int* __restrict__ tokexp, float* __restrict__ tokgate,
    int* __restrict__ cnt, float* __restrict__ gsum)
{
    const int t = blockIdx.x;
    const int tid = threadIdx.x;
    const int lane = tid & 63, wave = tid >> 6;
    __shared__ float wred[4];
    __shared__ float stats[2];
    __shared__ float lred[32];
    __shared__ float logitsS[8];

    float4 v = ((const float4*)(x + (size_t)t * DD))[tid];
    float s = v.x + v.y + v.z + v.w;
#pragma unroll
    for (int o = 32; o > 0; o >>= 1) s += __shfl_down(s, o, 64);
    if (lane == 0) wred[wave] = s;
    __syncthreads();
    if (tid == 0) stats[0] = (wred[0] + wred[1] + wred[2] + wred[3]) * (1.0f / DD);
    __syncthreads();
    const float mu = stats[0];
    float d0 = v.x - mu, d1 = v.y - mu, d2 = v.z - mu, d3 = v.w - mu;
    float q = d0*d0 + d1*d1 + d2*d2 + d3*d3;
#pragma unroll
    for (int o = 32; o > 0; o >>= 1) q += __shfl_down(q, o, 64);
    __syncthreads();   // protect wred reuse
    if (lane == 0) wred[wave] = q;
    __syncthreads();
    if (tid == 0) stats[1] = rsqrtf((wred[0]+wred[1]+wred[2]+wred[3]) * (1.0f / DD) + 1e-5f);
    __syncthreads();
    const float rstd = stats[1];
    float4 g4 = ((const float4*)gamma)[tid];
    float4 b4 = ((const float4*)beta)[tid];
    float n0 = d0 * rstd * g4.x + b4.x;
    float n1 = d1 * rstd * g4.y + b4.y;
    float n2 = d2 * rstd * g4.z + b4.z;
    float n3 = d3 * rstd * g4.w + b4.w;
    bf16x4 pk = { (bf16_t)n0, (bf16_t)n1, (bf16_t)n2, (bf16_t)n3 };
    ((bf16x4*)(xn + (size_t)t * DD))[tid] = pk;

    float part[8];
#pragma unroll
    for (int e = 0; e < 8; ++e) {
        float4 gw = ((const float4*)(gate_w + (size_t)e * DD))[tid];
        part[e] = n0 * gw.x + n1 * gw.y + n2 * gw.z + n3 * gw.w;
    }
#pragma unroll
    for (int e = 0; e < 8; ++e) {
        float p = part[e];
#pragma unroll
        for (int o = 32; o > 0; o >>= 1) p += __shfl_down(p, o, 64);
        if (lane == 0) lred[wave * 8 + e] = p;
    }
    __syncthreads();
    if (tid < 8) logitsS[tid] = lred[tid] + lred[8 + tid] + lred[16 + tid] + lred[24 + tid];
    __syncthreads();
    if (tid == 0) {
        float best = -1e30f; int e0 = 0;
        for (int e = 0; e < 8; ++e) { float le = logitsS[e]; if (le > best) { best = le; e0 = e; } }
        float best2 = -1e30f; int e1 = (e0 == 0) ? 1 : 0;
        for (int e = 0; e < 8; ++e) if (e != e0) { float le = logitsS[e]; if (le > best2) { best2 = le; e1 = e; } }
        float z = expf(best2 - best);
        float g0 = 1.0f / (1.0f + z);
        float g1 = z * g0;
        tokexp[2*t] = e0; tokexp[2*t+1] = e1;
        tokgate[2*t] = g0; tokgate[2*t+1] = g1;
        atomicAdd(&cnt[e0], 1); atomicAdd(&cnt[e1], 1);
        atomicAdd(&gsum[e0], g0); atomicAdd(&gsum[e1], g1);
    }
}

// ---------------- offsets + balance loss ----------------
__global__ void offs_bal_kernel(const int* __restrict__ cnt, const float* __restrict__ gsum,
                                int* __restrict__ offs, float* __restrict__ bal_out)
{
    if (threadIdx.x == 0) {
        int run = 0; float bal = 0.f;
        for (int e = 0; e < EE; ++e) {
            offs[e] = run; run += cnt[e];
            float l = gsum[e] * (1.0f / T_TOK) - (1.0f / EE);
            bal += l * l;
        }
        bal_out[0] = bal * (1.0f / EE);
    }
}

// ---------------- scatter to assignment-major lists ----------------
__global__ __launch_bounds__(256) void scatter_kernel(
    const int* __restrict__ tokexp, const float* __restrict__ tokgate,
    const int* __restrict__ offs, int* __restrict__ fill,
    int* __restrict__ tok, float* __restrict__ gatev, int* __restrict__ a_of_t)
{
    int t = blockIdx.x * 256 + threadIdx.x;
#pragma unroll
    for (int i = 0; i < 2; ++i) {
        int e = tokexp[2*t+i];
        int p = atomicAdd(&fill[e], 1);
        int a = offs[e] + p;
        tok[a] = t;
        gatev[a] = tokgate[2*t+i];
        a_of_t[2*t+i] = a;
    }
}

// ---------------- fp32 [E][R][C] -> bf16 [E][C][R] transpose ----------------
__global__ __launch_bounds__(256) void convT_kernel(
    const float* __restrict__ in, bf16_t* __restrict__ out, int R, int C)
{
    __shared__ float tile[64][65];
    int e = blockIdx.z;
    int c0 = blockIdx.x * 64, r0 = blockIdx.y * 64;
    int tx = threadIdx.x & 63, ty = threadIdx.x >> 6;
    const float* src = in + ((size_t)e * R + r0) * C + c0;
#pragma unroll
    for (int i = 0; i < 16; ++i) {
        int r = ty + i * 4;
        tile[r][tx] = src[(size_t)r * C + tx];
    }
    __syncthreads();
    bf16_t* dst = out + ((size_t)e * C + c0) * R + r0;
#pragma unroll
    for (int i = 0; i < 16; ++i) {
        int cc = ty + i * 4;
        dst[(size_t)cc * R + tx] = (bf16_t)tile[tx][cc];
    }
}

// ---------------- FFN1: h1 = gelu(xn[gathered] @ W1 + b1), bf16 out ----------------
__global__ __launch_bounds__(256) void ffn1_kernel(
    const bf16_t* __restrict__ xn, const bf16_t* __restrict__ w1t,
    const float* __restrict__ b1, const int* __restrict__ tok,
    const int* __restrict__ cnt, const int* __restrict__ offs,
    bf16_t* __restrict__ h1)
{
    const int e = blockIdx.z;
    const int c = cnt[e];
    const int m0 = blockIdx.y * 128;
    if (m0 >= c) return;
    const int n0 = blockIdx.x * 128;
    const int off = offs[e];

    __shared__ __align__(16) bf16_t As[128 * 32];
    __shared__ __align__(16) bf16_t Bs[128 * 32];

    const int tid = threadIdx.x;
    const int sr = tid >> 2;
    const int scol = (tid & 3) * 8;

    int ar0 = m0 + sr;      if (ar0 >= c) ar0 = c - 1;
    int ar1 = m0 + 64 + sr; if (ar1 >= c) ar1 = c - 1;
    const bf16_t* aptr0 = xn + (size_t)tok[off + ar0] * DD + scol;
    const bf16_t* aptr1 = xn + (size_t)tok[off + ar1] * DD + scol;
    const bf16_t* bptr0 = w1t + ((size_t)e * HH + n0 + sr) * DD + scol;
    const bf16_t* bptr1 = bptr0 + (size_t)64 * DD;

    bf16_t* ldsA0 = As + (size_t)tid * 8;
    bf16_t* ldsA1 = As + (size_t)(256 + tid) * 8;
    bf16_t* ldsB0 = Bs + (size_t)tid * 8;
    bf16_t* ldsB1 = Bs + (size_t)(256 + tid) * 8;

    const int lane = tid & 63;
    const int wave = tid >> 6;
    const int wr = wave >> 1, wc = wave & 1;
    const int mL = lane & 15, quad = lane >> 4;

    const bf16_t* Abase = As + ((wr * 64 + mL) * 32 + quad * 8);
    const bf16_t* Bbase = Bs + ((wc * 64 + mL) * 32 + quad * 8);

    f32x4 acc[4][4] = {};

    for (int k0 = 0; k0 < DD; k0 += 32) {
        GLDS(aptr0, ldsA0);
        GLDS(aptr1, ldsA1);
        GLDS(bptr0, ldsB0);
        GLDS(bptr1, ldsB1);
        aptr0 += 32; aptr1 += 32; bptr0 += 32; bptr1 += 32;
        __syncthreads();
        bf16x8 af[4], bfv[4];
#pragma unroll
        for (int i = 0; i < 4; ++i) af[i] = *(const bf16x8*)(Abase + i * 16 * 32);
#pragma unroll
        for (int j = 0; j < 4; ++j) bfv[j] = *(const bf16x8*)(Bbase + j * 16 * 32);
#pragma unroll
        for (int i = 0; i < 4; ++i)
#pragma unroll
            for (int j = 0; j < 4; ++j)
                acc[i][j] = __builtin_amdgcn_mfma_f32_16x16x32_bf16(af[i], bfv[j], acc[i][j], 0, 0, 0);
        __syncthreads();
    }

    const float* b1e = b1 + (size_t)e * HH;
#pragma unroll
    for (int i = 0; i < 4; ++i) {
#pragma unroll
        for (int r = 0; r < 4; ++r) {
            int m = m0 + wr * 64 + i * 16 + quad * 4 + r;
            if (m < c) {
                bf16_t* hrow = h1 + (size_t)(off + m) * HH;
#pragma unroll
                for (int j = 0; j < 4; ++j) {
                    int n = n0 + wc * 64 + j * 16 + mL;
                    float v = acc[i][j][r] + b1e[n];
                    v = 0.5f * v * (1.0f + erff(v * 0.70710678118654752f));
                    hrow[n] = (bf16_t)v;
                }
            }
        }
    }
}

// ---------------- FFN2: y = (h1 @ W2 + b2) * gate, bf16 out ----------------
__global__ __launch_bounds__(256) void ffn2_kernel(
    const bf16_t* __restrict__ h1, const bf16_t* __restrict__ w2t,
    const float* __restrict__ b2, const float* __restrict__ gatev,
    const int* __restrict__ cnt, const int* __restrict__ offs,
    bf16_t* __restrict__ yv)
{
    const int e = blockIdx.z;
    const int c = cnt[e];
    const int m0 = blockIdx.y * 128;
    if (m0 >= c) return;
    const int n0 = blockIdx.x * 128;
    const int off = offs[e];

    __shared__ __align__(16) bf16_t As[128 * 32];
    __shared__ __align__(16) bf16_t Bs[128 * 32];

    const int tid = threadIdx.x;
    const int sr = tid >> 2;
    const int scol = (tid & 3) * 8;

    int ar0 = m0 + sr;      if (ar0 >= c) ar0 = c - 1;
    int ar1 = m0 + 64 + sr; if (ar1 >= c) ar1 = c - 1;
    const bf16_t* aptr0 = h1 + (size_t)(off + ar0) * HH + scol;
    const bf16_t* aptr1 = h1 + (size_t)(off + ar1) * HH + scol;
    const bf16_t* bptr0 = w2t + ((size_t)e * DD + n0 + sr) * HH + scol;
    const bf16_t* bptr1 = bptr0 + (size_t)64 * HH;

    bf16_t* ldsA0 = As + (size_t)tid * 8;
    bf16_t* ldsA1 = As + (size_t)(256 + tid) * 8;
    bf16_t* ldsB0 = Bs + (size_t)tid * 8;
    bf16_t* ldsB1 = Bs + (size_t)(256 + tid) * 8;

    const int lane = tid & 63;
    const int wave = tid >> 6;
    const int wr = wave >> 1, wc = wave & 1;
    const int mL = lane & 15, quad = lane >> 4;

    const bf16_t* Abase = As + ((wr * 64 + mL) * 32 + quad * 8);
    const bf16_t* Bbase = Bs + ((wc * 64 + mL) * 32 + quad * 8);

    f32x4 acc[4][4] = {};

    for (int k0 = 0; k0 < HH; k0 += 32) {
        GLDS(aptr0, ldsA0);
        GLDS(aptr1, ldsA1);
        GLDS(bptr0, ldsB0);
        GLDS(bptr1, ldsB1);
        aptr0 += 32; aptr1 += 32; bptr0 += 32; bptr1 += 32;
        __syncthreads();
        bf16x8 af[4], bfv[4];
#pragma unroll
        for (int i = 0; i < 4; ++i) af[i] = *(const bf16x8*)(Abase + i * 16 * 32);
#pragma unroll
        for (int j = 0; j < 4; ++j) bfv[j] = *(const bf16x8*)(Bbase + j * 16 * 32);
#pragma unroll
        for (int i = 0; i < 4; ++i)
#pragma unroll
            for (int j = 0; j < 4; ++j)
                acc[i][j] = __builtin_amdgcn_mfma_f32_16x16x32_bf16(af[i], bfv[j], acc[i][j], 0, 0, 0);
        __syncthreads();
    }

    const float* b2e = b2 + (size_t)e * DD;
#pragma unroll
    for (int i = 0; i < 4; ++i) {
#pragma unroll
        for (int r = 0; r < 4; ++r) {
            int m = m0 + wr * 64 + i * 16 + quad * 4 + r;
            if (m < c) {
                float g = gatev[off + m];
                bf16_t* yrow = yv + (size_t)(off + m) * DD;
#pragma unroll
                for (int j = 0; j < 4; ++j) {
                    int n = n0 + wc * 64 + j * 16 + mL;
                    float v = (acc[i][j][r] + b2e[n]) * g;
                    yrow[n] = (bf16_t)v;
                }
            }
        }
    }
}

// ---------------- combine: out = x + y[a0] + y[a1] ----------------
__global__ __launch_bounds__(256) void combine_kernel(
    const float* __restrict__ x, const bf16_t* __restrict__ yv,
    const int* __restrict__ a_of_t, float* __restrict__ outp)
{
    int t = blockIdx.x;
    int tid = threadIdx.x;
    int a0 = a_of_t[2*t], a1 = a_of_t[2*t+1];
    float4 xv = ((const float4*)(x + (size_t)t * DD))[tid];
    bf16x4 y0 = ((const bf16x4*)(yv + (size_t)a0 * DD))[tid];
    bf16x4 y1 = ((const bf16x4*)(yv + (size_t)a1 * DD))[tid];
    float4 o;
    o.x = xv.x + (float)y0[0] + (float)y1[0];
    o.y = xv.y + (float)y0[1] + (float)y1[1];
    o.z = xv.z + (float)y0[2] + (float)y1[2];
    o.w = xv.w + (float)y0[3] + (float)y1[3];
    ((float4*)(outp + (size_t)t * DD))[tid] = o;
}

extern "C" void kernel_launch(void* const* d_in, const int* in_sizes, int n_in,
                              void* d_out, int out_size, void* d_ws, size_t ws_size,
                              hipStream_t stream)
{
    const float* x      = (const float*)d_in[0];
    const float* gamma  = (const float*)d_in[1];
    const float* beta   = (const float*)d_in[2];
    const float* gate_w = (const float*)d_in[3];
    const float* W1     = (const float*)d_in[4];
    const float* b1     = (const float*)d_in[5];
    const float* W2     = (const float*)d_in[6];
    const float* b2     = (const float*)d_in[7];
    float* outp = (float*)d_out;
    float* bal_out = outp + (size_t)T_TOK * DD;

    char* ws = (char*)d_ws;
    size_t off = 0;
    auto alloc = [&](size_t bytes) {
        char* p = ws + off;
        off += (bytes + 255) & ~(size_t)255;
        return p;
    };
    bf16_t* xn   = (bf16_t*)alloc((size_t)T_TOK * DD * 2);
    bf16_t* w1t  = (bf16_t*)alloc((size_t)EE * HH * DD * 2);
    bf16_t* w2t  = (bf16_t*)alloc((size_t)EE * DD * HH * 2);
    bf16_t* h1   = (bf16_t*)alloc((size_t)2 * T_TOK * HH * 2);
    bf16_t* yv   = (bf16_t*)alloc((size_t)2 * T_TOK * DD * 2);
    int*   tok     = (int*)alloc(2 * T_TOK * 4);
    float* gatev   = (float*)alloc(2 * T_TOK * 4);
    int*   a_of_t  = (int*)alloc(2 * T_TOK * 4);
    int*   tokexp  = (int*)alloc(2 * T_TOK * 4);
    float* tokgate = (float*)alloc(2 * T_TOK * 4);
    int*   cnt  = (int*)alloc(4 * EE * 4);       // cnt | gsum | offs | fill
    float* gsum = (float*)(cnt + EE);
    int*   offs = (int*)(cnt + 2 * EE);
    int*   fill = (int*)(cnt + 3 * EE);

    hipMemsetAsync(cnt, 0, 4 * EE * 4, stream);
    convT_kernel<<<dim3(HH/64, DD/64, EE), 256, 0, stream>>>(W1, w1t, DD, HH);
    convT_kernel<<<dim3(DD/64, HH/64, EE), 256, 0, stream>>>(W2, w2t, HH, DD);
    ln_gate_kernel<<<T_TOK, 256, 0, stream>>>(x, gamma, beta, gate_w, xn, tokexp, tokgate, cnt, gsum);
    offs_bal_kernel<<<1, 64, 0, stream>>>(cnt, gsum, offs, bal_out);
    scatter_kernel<<<T_TOK/256, 256, 0, stream>>>(tokexp, tokgate, offs, fill, tok, gatev, a_of_t);
    ffn1_kernel<<<dim3(HH/128, 64, EE), 256, 0, stream>>>(xn, w1t, b1, tok, cnt, offs, h1);
    ffn2_kernel<<<dim3(DD/128, 64, EE), 256, 0, stream>>>(h1, w2t, b2, gatev, cnt, offs, yv);
    combine_kernel<<<T_TOK, 256, 0, stream>>>(x, yv, a_of_t, outp);
}

// Round 2
// 870.679 us; speedup vs baseline: 1.5128x; 1.5128x over previous
//
#include <hip/hip_runtime.h>
#include <hip/hip_bf16.h>

#define T_TOK 8192
#define DD 1024
#define EE 8
#define HH 4096
#define NA (2 * T_TOK)          // 16384 assignments
#define NBLK (NA / 256)         // 64 histogram/scatter blocks

typedef __bf16 bf16_t;
typedef __bf16 bf16x8 __attribute__((ext_vector_type(8)));
typedef __bf16 bf16x4 __attribute__((ext_vector_type(4)));
typedef float f32x4 __attribute__((ext_vector_type(4)));

#define GLDS(g, l) __builtin_amdgcn_global_load_lds( \
    (const __attribute__((address_space(1))) void*)(g), \
    (__attribute__((address_space(3))) void*)(l), 16, 0, 0)

// ---------------- LayerNorm + gating (NO global atomics) ----------------
__global__ __launch_bounds__(256) void ln_gate_kernel(
    const float* __restrict__ x, const float* __restrict__ gamma,
    const float* __restrict__ beta, const float* __restrict__ gate_w,
    bf16_t* __restrict__ xn, int* __restrict__ tokexp, float* __restrict__ tokgate)
{
    const int t = blockIdx.x;
    const int tid = threadIdx.x;
    const int lane = tid & 63, wave = tid >> 6;
    __shared__ float wred[4];
    __shared__ float stats[2];
    __shared__ float lred[32];
    __shared__ float logitsS[8];

    float4 v = ((const float4*)(x + (size_t)t * DD))[tid];
    float s = v.x + v.y + v.z + v.w;
#pragma unroll
    for (int o = 32; o > 0; o >>= 1) s += __shfl_down(s, o, 64);
    if (lane == 0) wred[wave] = s;
    __syncthreads();
    if (tid == 0) stats[0] = (wred[0] + wred[1] + wred[2] + wred[3]) * (1.0f / DD);
    __syncthreads();
    const float mu = stats[0];
    float d0 = v.x - mu, d1 = v.y - mu, d2 = v.z - mu, d3 = v.w - mu;
    float q = d0*d0 + d1*d1 + d2*d2 + d3*d3;
#pragma unroll
    for (int o = 32; o > 0; o >>= 1) q += __shfl_down(q, o, 64);
    __syncthreads();
    if (lane == 0) wred[wave] = q;
    __syncthreads();
    if (tid == 0) stats[1] = rsqrtf((wred[0]+wred[1]+wred[2]+wred[3]) * (1.0f / DD) + 1e-5f);
    __syncthreads();
    const float rstd = stats[1];
    float4 g4 = ((const float4*)gamma)[tid];
    float4 b4 = ((const float4*)beta)[tid];
    float n0 = d0 * rstd * g4.x + b4.x;
    float n1 = d1 * rstd * g4.y + b4.y;
    float n2 = d2 * rstd * g4.z + b4.z;
    float n3 = d3 * rstd * g4.w + b4.w;
    bf16x4 pk = { (bf16_t)n0, (bf16_t)n1, (bf16_t)n2, (bf16_t)n3 };
    ((bf16x4*)(xn + (size_t)t * DD))[tid] = pk;

    float part[8];
#pragma unroll
    for (int e = 0; e < 8; ++e) {
        float4 gw = ((const float4*)(gate_w + (size_t)e * DD))[tid];
        part[e] = n0 * gw.x + n1 * gw.y + n2 * gw.z + n3 * gw.w;
    }
#pragma unroll
    for (int e = 0; e < 8; ++e) {
        float p = part[e];
#pragma unroll
        for (int o = 32; o > 0; o >>= 1) p += __shfl_down(p, o, 64);
        if (lane == 0) lred[wave * 8 + e] = p;
    }
    __syncthreads();
    if (tid < 8) logitsS[tid] = lred[tid] + lred[8 + tid] + lred[16 + tid] + lred[24 + tid];
    __syncthreads();
    if (tid == 0) {
        float best = -1e30f; int e0 = 0;
        for (int e = 0; e < 8; ++e) { float le = logitsS[e]; if (le > best) { best = le; e0 = e; } }
        float best2 = -1e30f; int e1 = (e0 == 0) ? 1 : 0;
        for (int e = 0; e < 8; ++e) if (e != e0) { float le = logitsS[e]; if (le > best2) { best2 = le; e1 = e; } }
        float z = expf(best2 - best);
        float g0 = 1.0f / (1.0f + z);
        float g1 = z * g0;
        tokexp[2*t] = e0; tokexp[2*t+1] = e1;
        tokgate[2*t] = g0; tokgate[2*t+1] = g1;
    }
}

// ---------------- per-block histogram (LDS atomics only) ----------------
__global__ __launch_bounds__(256) void hist_kernel(
    const int* __restrict__ tokexp, const float* __restrict__ tokgate,
    int* __restrict__ blockcnt, float* __restrict__ blockgsum)
{
    __shared__ int hcnt[EE];
    __shared__ float hg[EE];
    const int b = blockIdx.x, tid = threadIdx.x;
    if (tid < EE) { hcnt[tid] = 0; hg[tid] = 0.f; }
    __syncthreads();
    int idx = b * 256 + tid;
    int e = tokexp[idx];
    atomicAdd(&hcnt[e], 1);
    atomicAdd(&hg[e], tokgate[idx]);
    __syncthreads();
    if (tid < EE) {
        blockcnt[b * EE + tid] = hcnt[tid];
        blockgsum[b * EE + tid] = hg[tid];
    }
}

// ---------------- offsets + per-block bases + balance loss ----------------
__global__ __launch_bounds__(64) void offs_bal_kernel(
    const int* __restrict__ blockcnt, const float* __restrict__ blockgsum,
    int* __restrict__ cnt, int* __restrict__ offs, int* __restrict__ basep,
    float* __restrict__ bal_out)
{
    __shared__ int cntS[EE];
    const int tid = threadIdx.x;
    if (tid < EE) {
        int run = 0;
        for (int b = 0; b < NBLK; ++b) {
            basep[b * EE + tid] = run;
            run += blockcnt[b * EE + tid];
        }
        cnt[tid] = run;
        cntS[tid] = run;
    }
    __syncthreads();
    __shared__ int offsS[EE];
    if (tid == 0) {
        int run = 0; 
        for (int e = 0; e < EE; ++e) { offsS[e] = run; offs[e] = run; run += cntS[e]; }
        float bal = 0.f;
        for (int e = 0; e < EE; ++e) {
            float g = 0.f;
            for (int b = 0; b < NBLK; ++b) g += blockgsum[b * EE + e];
            float l = g * (1.0f / T_TOK) - (1.0f / EE);
            bal += l * l;
        }
        bal_out[0] = bal * (1.0f / EE);
    }
    __syncthreads();
    if (tid < EE) {
        for (int b = 0; b < NBLK; ++b) basep[b * EE + tid] += offsS[tid];
    }
}

// ---------------- scatter to assignment-major lists (LDS atomics only) ----------------
__global__ __launch_bounds__(256) void scatter_kernel(
    const int* __restrict__ tokexp, const float* __restrict__ tokgate,
    const int* __restrict__ basep,
    int* __restrict__ tok, float* __restrict__ gatev, int* __restrict__ a_of_t)
{
    __shared__ int hcnt[EE];
    const int b = blockIdx.x, tid = threadIdx.x;
    if (tid < EE) hcnt[tid] = 0;
    __syncthreads();
    int idx = b * 256 + tid;
    int e = tokexp[idx];
    int r = atomicAdd(&hcnt[e], 1);
    int a = basep[b * EE + e] + r;
    tok[a] = idx >> 1;
    gatev[a] = tokgate[idx];
    a_of_t[idx] = a;
}

// ---------------- fp32 [E][R][C] -> bf16 [E][C][R] transpose ----------------
__global__ __launch_bounds__(256) void convT_kernel(
    const float* __restrict__ in, bf16_t* __restrict__ out, int R, int C)
{
    __shared__ float tile[64][65];
    int e = blockIdx.z;
    int c0 = blockIdx.x * 64, r0 = blockIdx.y * 64;
    int tx = threadIdx.x & 63, ty = threadIdx.x >> 6;
    const float* src = in + ((size_t)e * R + r0) * C + c0;
#pragma unroll
    for (int i = 0; i < 16; ++i) {
        int r = ty + i * 4;
        tile[r][tx] = src[(size_t)r * C + tx];
    }
    __syncthreads();
    bf16_t* dst = out + ((size_t)e * C + c0) * R + r0;
#pragma unroll
    for (int i = 0; i < 16; ++i) {
        int cc = ty + i * 4;
        dst[(size_t)cc * R + tx] = (bf16_t)tile[tx][cc];
    }
}

// ---------------- FFN1: h1 = gelu(xn[gathered] @ W1 + b1), bf16 out ----------------
__global__ __launch_bounds__(256) void ffn1_kernel(
    const bf16_t* __restrict__ xn, const bf16_t* __restrict__ w1t,
    const float* __restrict__ b1, const int* __restrict__ tok,
    const int* __restrict__ cnt, const int* __restrict__ offs,
    bf16_t* __restrict__ h1)
{
    const int e = blockIdx.z;
    const int c = cnt[e];
    const int m0 = blockIdx.y * 128;
    if (m0 >= c) return;
    const int n0 = blockIdx.x * 128;
    const int off = offs[e];

    __shared__ __align__(16) bf16_t As[128 * 32];
    __shared__ __align__(16) bf16_t Bs[128 * 32];

    const int tid = threadIdx.x;
    const int sr = tid >> 2;
    const int scol = (tid & 3) * 8;

    int ar0 = m0 + sr;      if (ar0 >= c) ar0 = c - 1;
    int ar1 = m0 + 64 + sr; if (ar1 >= c) ar1 = c - 1;
    const bf16_t* aptr0 = xn + (size_t)tok[off + ar0] * DD + scol;
    const bf16_t* aptr1 = xn + (size_t)tok[off + ar1] * DD + scol;
    const bf16_t* bptr0 = w1t + ((size_t)e * HH + n0 + sr) * DD + scol;
    const bf16_t* bptr1 = bptr0 + (size_t)64 * DD;

    bf16_t* ldsA0 = As + (size_t)tid * 8;
    bf16_t* ldsA1 = As + (size_t)(256 + tid) * 8;
    bf16_t* ldsB0 = Bs + (size_t)tid * 8;
    bf16_t* ldsB1 = Bs + (size_t)(256 + tid) * 8;

    const int lane = tid & 63;
    const int wave = tid >> 6;
    const int wr = wave >> 1, wc = wave & 1;
    const int mL = lane & 15, quad = lane >> 4;

    const bf16_t* Abase = As + ((wr * 64 + mL) * 32 + quad * 8);
    const bf16_t* Bbase = Bs + ((wc * 64 + mL) * 32 + quad * 8);

    f32x4 acc[4][4] = {};

    for (int k0 = 0; k0 < DD; k0 += 32) {
        GLDS(aptr0, ldsA0);
        GLDS(aptr1, ldsA1);
        GLDS(bptr0, ldsB0);
        GLDS(bptr1, ldsB1);
        aptr0 += 32; aptr1 += 32; bptr0 += 32; bptr1 += 32;
        __syncthreads();
        bf16x8 af[4], bfv[4];
#pragma unroll
        for (int i = 0; i < 4; ++i) af[i] = *(const bf16x8*)(Abase + i * 16 * 32);
#pragma unroll
        for (int j = 0; j < 4; ++j) bfv[j] = *(const bf16x8*)(Bbase + j * 16 * 32);
#pragma unroll
        for (int i = 0; i < 4; ++i)
#pragma unroll
            for (int j = 0; j < 4; ++j)
                acc[i][j] = __builtin_amdgcn_mfma_f32_16x16x32_bf16(af[i], bfv[j], acc[i][j], 0, 0, 0);
        __syncthreads();
    }

    const float* b1e = b1 + (size_t)e * HH;
#pragma unroll
    for (int i = 0; i < 4; ++i) {
#pragma unroll
        for (int r = 0; r < 4; ++r) {
            int m = m0 + wr * 64 + i * 16 + quad * 4 + r;
            if (m < c) {
                bf16_t* hrow = h1 + (size_t)(off + m) * HH;
#pragma unroll
                for (int j = 0; j < 4; ++j) {
                    int n = n0 + wc * 64 + j * 16 + mL;
                    float v = acc[i][j][r] + b1e[n];
                    v = 0.5f * v * (1.0f + erff(v * 0.70710678118654752f));
                    hrow[n] = (bf16_t)v;
                }
            }
        }
    }
}

// ---------------- FFN2: y = (h1 @ W2 + b2) * gate, bf16 out ----------------
__global__ __launch_bounds__(256) void ffn2_kernel(
    const bf16_t* __restrict__ h1, const bf16_t* __restrict__ w2t,
    const float* __restrict__ b2, const float* __restrict__ gatev,
    const int* __restrict__ cnt, const int* __restrict__ offs,
    bf16_t* __restrict__ yv)
{
    const int e = blockIdx.z;
    const int c = cnt[e];
    const int m0 = blockIdx.y * 128;
    if (m0 >= c) return;
    const int n0 = blockIdx.x * 128;
    const int off = offs[e];

    __shared__ __align__(16) bf16_t As[128 * 32];
    __shared__ __align__(16) bf16_t Bs[128 * 32];

    const int tid = threadIdx.x;
    const int sr = tid >> 2;
    const int scol = (tid & 3) * 8;

    int ar0 = m0 + sr;      if (ar0 >= c) ar0 = c - 1;
    int ar1 = m0 + 64 + sr; if (ar1 >= c) ar1 = c - 1;
    const bf16_t* aptr0 = h1 + (size_t)(off + ar0) * HH + scol;
    const bf16_t* aptr1 = h1 + (size_t)(off + ar1) * HH + scol;
    const bf16_t* bptr0 = w2t + ((size_t)e * DD + n0 + sr) * HH + scol;
    const bf16_t* bptr1 = bptr0 + (size_t)64 * HH;

    bf16_t* ldsA0 = As + (size_t)tid * 8;
    bf16_t* ldsA1 = As + (size_t)(256 + tid) * 8;
    bf16_t* ldsB0 = Bs + (size_t)tid * 8;
    bf16_t* ldsB1 = Bs + (size_t)(256 + tid) * 8;

    const int lane = tid & 63;
    const int wave = tid >> 6;
    const int wr = wave >> 1, wc = wave & 1;
    const int mL = lane & 15, quad = lane >> 4;

    const bf16_t* Abase = As + ((wr * 64 + mL) * 32 + quad * 8);
    const bf16_t* Bbase = Bs + ((wc * 64 + mL) * 32 + quad * 8);

    f32x4 acc[4][4] = {};

    for (int k0 = 0; k0 < HH; k0 += 32) {
        GLDS(aptr0, ldsA0);
        GLDS(aptr1, ldsA1);
        GLDS(bptr0, ldsB0);
        GLDS(bptr1, ldsB1);
        aptr0 += 32; aptr1 += 32; bptr0 += 32; bptr1 += 32;
        __syncthreads();
        bf16x8 af[4], bfv[4];
#pragma unroll
        for (int i = 0; i < 4; ++i) af[i] = *(const bf16x8*)(Abase + i * 16 * 32);
#pragma unroll
        for (int j = 0; j < 4; ++j) bfv[j] = *(const bf16x8*)(Bbase + j * 16 * 32);
#pragma unroll
        for (int i = 0; i < 4; ++i)
#pragma unroll
            for (int j = 0; j < 4; ++j)
                acc[i][j] = __builtin_amdgcn_mfma_f32_16x16x32_bf16(af[i], bfv[j], acc[i][j], 0, 0, 0);
        __syncthreads();
    }

    const float* b2e = b2 + (size_t)e * DD;
#pragma unroll
    for (int i = 0; i < 4; ++i) {
#pragma unroll
        for (int r = 0; r < 4; ++r) {
            int m = m0 + wr * 64 + i * 16 + quad * 4 + r;
            if (m < c) {
                float g = gatev[off + m];
                bf16_t* yrow = yv + (size_t)(off + m) * DD;
#pragma unroll
                for (int j = 0; j < 4; ++j) {
                    int n = n0 + wc * 64 + j * 16 + mL;
                    float v = (acc[i][j][r] + b2e[n]) * g;
                    yrow[n] = (bf16_t)v;
                }
            }
        }
    }
}

// ---------------- combine: out = x + y[a0] + y[a1] ----------------
__global__ __launch_bounds__(256) void combine_kernel(
    const float* __restrict__ x, const bf16_t* __restrict__ yv,
    const int* __restrict__ a_of_t, float* __restrict__ outp)
{
    int t = blockIdx.x;
    int tid = threadIdx.x;
    int a0 = a_of_t[2*t], a1 = a_of_t[2*t+1];
    float4 xv = ((const float4*)(x + (size_t)t * DD))[tid];
    bf16x4 y0 = ((const bf16x4*)(yv + (size_t)a0 * DD))[tid];
    bf16x4 y1 = ((const bf16x4*)(yv + (size_t)a1 * DD))[tid];
    float4 o;
    o.x = xv.x + (float)y0[0] + (float)y1[0];
    o.y = xv.y + (float)y0[1] + (float)y1[1];
    o.z = xv.z + (float)y0[2] + (float)y1[2];
    o.w = xv.w + (float)y0[3] + (float)y1[3];
    ((float4*)(outp + (size_t)t * DD))[tid] = o;
}

extern "C" void kernel_launch(void* const* d_in, const int* in_sizes, int n_in,
                              void* d_out, int out_size, void* d_ws, size_t ws_size,
                              hipStream_t stream)
{
    const float* x      = (const float*)d_in[0];
    const float* gamma  = (const float*)d_in[1];
    const float* beta   = (const float*)d_in[2];
    const float* gate_w = (const float*)d_in[3];
    const float* W1     = (const float*)d_in[4];
    const float* b1     = (const float*)d_in[5];
    const float* W2     = (const float*)d_in[6];
    const float* b2     = (const float*)d_in[7];
    float* outp = (float*)d_out;
    float* bal_out = outp + (size_t)T_TOK * DD;

    char* ws = (char*)d_ws;
    size_t off = 0;
    auto alloc = [&](size_t bytes) {
        char* p = ws + off;
        off += (bytes + 255) & ~(size_t)255;
        return p;
    };
    bf16_t* xn   = (bf16_t*)alloc((size_t)T_TOK * DD * 2);
    bf16_t* w1t  = (bf16_t*)alloc((size_t)EE * HH * DD * 2);
    bf16_t* w2t  = (bf16_t*)alloc((size_t)EE * DD * HH * 2);
    bf16_t* h1   = (bf16_t*)alloc((size_t)NA * HH * 2);
    bf16_t* yv   = (bf16_t*)alloc((size_t)NA * DD * 2);
    int*   tok     = (int*)alloc(NA * 4);
    float* gatev   = (float*)alloc(NA * 4);
    int*   a_of_t  = (int*)alloc(NA * 4);
    int*   tokexp  = (int*)alloc(NA * 4);
    float* tokgate = (float*)alloc(NA * 4);
    int*   blockcnt  = (int*)alloc(NBLK * EE * 4);
    float* blockgsum = (float*)alloc(NBLK * EE * 4);
    int*   basep     = (int*)alloc(NBLK * EE * 4);
    int*   cnt  = (int*)alloc(EE * 4);
    int*   offs = (int*)alloc(EE * 4);

    convT_kernel<<<dim3(HH/64, DD/64, EE), 256, 0, stream>>>(W1, w1t, DD, HH);
    convT_kernel<<<dim3(DD/64, HH/64, EE), 256, 0, stream>>>(W2, w2t, HH, DD);
    ln_gate_kernel<<<T_TOK, 256, 0, stream>>>(x, gamma, beta, gate_w, xn, tokexp, tokgate);
    hist_kernel<<<NBLK, 256, 0, stream>>>(tokexp, tokgate, blockcnt, blockgsum);
    offs_bal_kernel<<<1, 64, 0, stream>>>(blockcnt, blockgsum, cnt, offs, basep, bal_out);
    scatter_kernel<<<NBLK, 256, 0, stream>>>(tokexp, tokgate, basep, tok, gatev, a_of_t);
    ffn1_kernel<<<dim3(HH/128, 64, EE), 256, 0, stream>>>(xn, w1t, b1, tok, cnt, offs, h1);
    ffn2_kernel<<<dim3(DD/128, 64, EE), 256, 0, stream>>>(h1, w2t, b2, gatev, cnt, offs, yv);
    combine_kernel<<<T_TOK, 256, 0, stream>>>(x, yv, a_of_t, outp);
}